// Round 1
// baseline (357.243 us; speedup 1.0000x reference)
//
#include <hip/hip_runtime.h>
#include <hip/hip_fp16.h>

typedef _Float16 f16;
typedef _Float16 half8 __attribute__((ext_vector_type(8)));
typedef _Float16 half4v __attribute__((ext_vector_type(4)));
typedef float floatx4 __attribute__((ext_vector_type(4)));

constexpr int Bsz = 4, Tseq = 2048, Cdim = 1024, NH = 16, HDim = 64;
constexpr int Mtok = Bsz * Tseq;      // 8192
constexpr int N_QKV = 3 * Cdim;       // 3072

#define GLDS16(src, dst) __builtin_amdgcn_global_load_lds( \
    (const __attribute__((address_space(1))) void*)(src),  \
    (__attribute__((address_space(3))) void*)(dst), 16, 0, 0)

// ---------------- f32 -> f16 conversion ----------------
__global__ void cvt_kernel(const float* __restrict__ in, f16* __restrict__ out, int n) {
  int i = (blockIdx.x * blockDim.x + threadIdx.x) * 4;
  if (i >= n) return;
  float4 v = *(const float4*)(in + i);
  half4v o;
  o[0] = (f16)v.x; o[1] = (f16)v.y; o[2] = (f16)v.z; o[3] = (f16)v.w;
  *(half4v*)(out + i) = o;
}

// ---------------- GEMM: C[m][n] = sum_k X[m][k] * W[n][k] ----------------
// EPI 0: scatter q/k/v as f16 [B,H,T,HD];  EPI 1: store f32 row-major
template<int EPI>
__global__ __launch_bounds__(256)
void gemm_kernel(const f16* __restrict__ X, const f16* __restrict__ W,
                 float* __restrict__ outF,
                 f16* __restrict__ q_out, f16* __restrict__ k_out, f16* __restrict__ v_out,
                 int M, int N, int K)
{
  constexpr int BM = 128, BN = 128, BK = 32;
  __shared__ __align__(16) f16 As[BM * BK];   // [row][32], 64B rows, col-group swizzled
  __shared__ __align__(16) f16 Bs[BN * BK];
  const int tid = threadIdx.x;
  const int wave = tid >> 6;
  const int lane = tid & 63;
  const int g = lane >> 4, lm = lane & 15;
  const int nbn = N / BN;
  const int bm = blockIdx.x / nbn;
  const int bn = blockIdx.x % nbn;
  const int m0 = bm * BM, n0 = bn * BN;
  const int wr = wave >> 1, wc = wave & 1;   // 2x2 waves, 64x64 each

  floatx4 acc[4][4];
#pragma unroll
  for (int i = 0; i < 4; ++i)
#pragma unroll
    for (int j = 0; j < 4; ++j) acc[i][j] = (floatx4)0.0f;

  for (int k0 = 0; k0 < K; k0 += BK) {
    __syncthreads();
#pragma unroll
    for (int t = 0; t < 2; ++t) {
      // this wave-instruction covers 16 rows; lane i -> row +i/4, phys col-group i%4
      int row = (wave * 2 + t) * 16 + (lane >> 2);
      int cg = (lane & 3) ^ ((row >> 1) & 3);   // logical col-group to fetch (pre-swizzled src)
      const f16* srcA = X + (size_t)(m0 + row) * K + k0 + cg * 8;
      GLDS16(srcA, (char*)As + (wave * 2 + t) * 1024);
      const f16* srcB = W + (size_t)(n0 + row) * K + k0 + cg * 8;
      GLDS16(srcB, (char*)Bs + (wave * 2 + t) * 1024);
    }
    __syncthreads();

    half8 af[4], bf[4];
#pragma unroll
    for (int i = 0; i < 4; ++i) {
      int rowa = wr * 64 + i * 16 + lm;
      int cga = g ^ ((rowa >> 1) & 3);
      af[i] = *(const half8*)((const char*)As + rowa * 64 + cga * 16);
      int rowb = wc * 64 + i * 16 + lm;
      int cgb = g ^ ((rowb >> 1) & 3);
      bf[i] = *(const half8*)((const char*)Bs + rowb * 64 + cgb * 16);
    }
#pragma unroll
    for (int i = 0; i < 4; ++i)
#pragma unroll
      for (int j = 0; j < 4; ++j)
        acc[i][j] = __builtin_amdgcn_mfma_f32_16x16x32_f16(af[i], bf[j], acc[i][j], 0, 0, 0);
  }

  // D layout: row = 4*(lane>>4)+r, col = lane&15
#pragma unroll
  for (int i = 0; i < 4; ++i) {
#pragma unroll
    for (int j = 0; j < 4; ++j) {
#pragma unroll
      for (int r = 0; r < 4; ++r) {
        int m = m0 + wr * 64 + i * 16 + 4 * g + r;
        int n = n0 + wc * 64 + j * 16 + lm;
        float v = acc[i][j][r];
        if constexpr (EPI == 1) {
          outF[(size_t)m * N + n] = v;
        } else {
          int which = n >> 10;
          int inner = n & 1023;
          int h = inner >> 6, hd = inner & 63;
          int b = m >> 11, t = m & 2047;
          f16* dst = which == 0 ? q_out : (which == 1 ? k_out : v_out);
          dst[(((size_t)(b * NH + h)) * Tseq + t) * HDim + hd] = (f16)v;
        }
      }
    }
  }
}

// ---------------- causal flash attention ----------------
// grid: (T/64, B*H). 4 waves x 16 q-rows. Q,K,V f16 [B,H,T,HD]; Y f16 [B,T,C]
__global__ __launch_bounds__(256)
void attn_kernel(const f16* __restrict__ Q, const f16* __restrict__ Kg,
                 const f16* __restrict__ V, f16* __restrict__ Y)
{
  constexpr int QBLK = 64, KVBLK = 64, PAD = 72;  // pad rows to 144B -> 2-way max conflicts
  __shared__ __align__(16) f16 Ks[KVBLK][PAD];    // [kv][hd]
  __shared__ __align__(16) f16 Vts[HDim][PAD];    // [hd][kv]  (transposed)
  __shared__ __align__(16) f16 Ps[4][16][PAD];    // per-wave P tile [q][kv]
  const int qt = blockIdx.x;
  const int bh = blockIdx.y;
  const f16* Qb = Q + (size_t)bh * Tseq * HDim;
  const f16* Kb = Kg + (size_t)bh * Tseq * HDim;
  const f16* Vb = V + (size_t)bh * Tseq * HDim;
  const int tid = threadIdx.x, wave = tid >> 6, lane = tid & 63;
  const int g = lane >> 4, lm = lane & 15;
  const int q0 = qt * QBLK;
  const int qrow = q0 + wave * 16 + lm;

  // Q fragments held in registers for the whole kernel
  half8 qf0 = *(const half8*)(Qb + (size_t)qrow * HDim + g * 8);
  half8 qf1 = *(const half8*)(Qb + (size_t)qrow * HDim + 32 + g * 8);

  float m_run[4], l_run[4];
  floatx4 acc[4];
#pragma unroll
  for (int r = 0; r < 4; ++r) { m_run[r] = -1e30f; l_run[r] = 0.f; }
#pragma unroll
  for (int ng = 0; ng < 4; ++ng) acc[ng] = (floatx4)0.f;

  const float scale = 0.125f;  // 1/sqrt(64)
  const int ntiles = qt + 1;

  const int skv = tid >> 2, sc = (tid & 3) * 16;      // K staging map
  const int vkv = tid & 63, vh0 = (tid >> 6) * 16;    // V staging map

  for (int jt = 0; jt < ntiles; ++jt) {
    const int j0 = jt * KVBLK;
    __syncthreads();
    {
      const f16* krow = Kb + (size_t)(j0 + skv) * HDim + sc;
      *(half8*)&Ks[skv][sc]     = *(const half8*)krow;
      *(half8*)&Ks[skv][sc + 8] = *(const half8*)(krow + 8);
      const f16* vrow = Vb + (size_t)(j0 + vkv) * HDim + vh0;
      half8 v0 = *(const half8*)vrow;
      half8 v1 = *(const half8*)(vrow + 8);
#pragma unroll
      for (int i = 0; i < 8; ++i) {
        Vts[vh0 + i][vkv]     = v0[i];
        Vts[vh0 + 8 + i][vkv] = v1[i];
      }
    }
    __syncthreads();

    // S = Q K^T  (D: row q = 4g+r, col kv = nf*16+lm)
    floatx4 s[4];
#pragma unroll
    for (int nf = 0; nf < 4; ++nf) {
      s[nf] = (floatx4)0.f;
      half8 kf0 = *(const half8*)&Ks[nf * 16 + lm][g * 8];
      s[nf] = __builtin_amdgcn_mfma_f32_16x16x32_f16(qf0, kf0, s[nf], 0, 0, 0);
      half8 kf1 = *(const half8*)&Ks[nf * 16 + lm][32 + g * 8];
      s[nf] = __builtin_amdgcn_mfma_f32_16x16x32_f16(qf1, kf1, s[nf], 0, 0, 0);
    }

    const bool diag = (jt == qt);
#pragma unroll
    for (int r = 0; r < 4; ++r) {
      const int qg = q0 + wave * 16 + 4 * g + r;
      float sv[4];
#pragma unroll
      for (int nf = 0; nf < 4; ++nf) {
        float v = s[nf][r] * scale;
        if (diag) {
          int kvg = j0 + nf * 16 + lm;
          if (kvg > qg) v = -1e30f;
        }
        sv[nf] = v;
      }
      float mx = fmaxf(fmaxf(sv[0], sv[1]), fmaxf(sv[2], sv[3]));
#pragma unroll
      for (int off = 1; off < 16; off <<= 1)
        mx = fmaxf(mx, __shfl_xor(mx, off, 64));
      float newm = fmaxf(m_run[r], mx);
      float sc_old = __expf(m_run[r] - newm);
      float rs = 0.f;
      f16 pcvt[4];
#pragma unroll
      for (int nf = 0; nf < 4; ++nf) {
        float pv = __expf(sv[nf] - newm);
        rs += pv;
        pcvt[nf] = (f16)pv;
      }
#pragma unroll
      for (int off = 1; off < 16; off <<= 1)
        rs += __shfl_xor(rs, off, 64);
      l_run[r] = l_run[r] * sc_old + rs;
      m_run[r] = newm;
#pragma unroll
      for (int ng = 0; ng < 4; ++ng) acc[ng][r] *= sc_old;
#pragma unroll
      for (int nf = 0; nf < 4; ++nf)
        Ps[wave][4 * g + r][nf * 16 + lm] = pcvt[nf];
    }

    // PV: A = P [16q x 64kv], B = V^T rows (hd) contiguous in kv. Wave-local LDS, no barrier.
    half8 pa0 = *(const half8*)&Ps[wave][lm][g * 8];
    half8 pa1 = *(const half8*)&Ps[wave][lm][32 + g * 8];
#pragma unroll
    for (int ng = 0; ng < 4; ++ng) {
      half8 vb0 = *(const half8*)&Vts[ng * 16 + lm][g * 8];
      acc[ng] = __builtin_amdgcn_mfma_f32_16x16x32_f16(pa0, vb0, acc[ng], 0, 0, 0);
      half8 vb1 = *(const half8*)&Vts[ng * 16 + lm][32 + g * 8];
      acc[ng] = __builtin_amdgcn_mfma_f32_16x16x32_f16(pa1, vb1, acc[ng], 0, 0, 0);
    }
  }

  const int b = bh >> 4, h = bh & 15;
#pragma unroll
  for (int r = 0; r < 4; ++r) {
    float inv = 1.0f / l_run[r];
    int t = q0 + wave * 16 + 4 * g + r;
    size_t base = ((size_t)(b * Tseq + t)) * Cdim + h * HDim;
#pragma unroll
    for (int ng = 0; ng < 4; ++ng)
      Y[base + ng * 16 + lm] = (f16)(acc[ng][r] * inv);
  }
}

// ---------------- launcher ----------------
extern "C" void kernel_launch(void* const* d_in, const int* in_sizes, int n_in,
                              void* d_out, int out_size, void* d_ws, size_t ws_size,
                              hipStream_t stream)
{
  const float* x      = (const float*)d_in[0];
  const float* W_attn = (const float*)d_in[1];
  const float* W_proj = (const float*)d_in[2];
  float* out = (float*)d_out;

  char* ws = (char*)d_ws;
  f16* xh  = (f16*)(ws);                        // 16 MB (reused as yh after attention)
  f16* wAh = (f16*)(ws + (size_t)(16u << 20));  // 6 MB
  f16* wPh = (f16*)(ws + (size_t)(22u << 20));  // 2 MB
  f16* Qh  = (f16*)(ws + (size_t)(24u << 20));  // 16 MB
  f16* Kh  = (f16*)(ws + (size_t)(40u << 20));  // 16 MB
  f16* Vh  = (f16*)(ws + (size_t)(56u << 20));  // 16 MB
  f16* yh  = xh;

  const int nx  = Mtok * Cdim;     // 8388608
  const int nwa = N_QKV * Cdim;    // 3145728
  const int nwp = Cdim * Cdim;     // 1048576
  cvt_kernel<<<(nx / 4 + 255) / 256, 256, 0, stream>>>(x, xh, nx);
  cvt_kernel<<<(nwa / 4 + 255) / 256, 256, 0, stream>>>(W_attn, wAh, nwa);
  cvt_kernel<<<(nwp / 4 + 255) / 256, 256, 0, stream>>>(W_proj, wPh, nwp);

  gemm_kernel<0><<<dim3((Mtok / 128) * (N_QKV / 128)), 256, 0, stream>>>(
      xh, wAh, nullptr, Qh, Kh, Vh, Mtok, N_QKV, Cdim);

  attn_kernel<<<dim3(Tseq / 64, Bsz * NH), 256, 0, stream>>>(Qh, Kh, Vh, yh);

  gemm_kernel<1><<<dim3((Mtok / 128) * (Cdim / 128)), 256, 0, stream>>>(
      yh, wPh, out, nullptr, nullptr, nullptr, Mtok, Cdim, Cdim);
}